// Round 9
// baseline (133.788 us; speedup 1.0000x reference)
//
#include <hip/hip_runtime.h>
#include <hip/hip_bf16.h>
#include <cstdint>
#include <cstddef>

using bf16 = __hip_bfloat16;
typedef __attribute__((ext_vector_type(8))) short short8v;
typedef __attribute__((ext_vector_type(4))) float f32x4;

static constexpr int BATCH = 32;
static constexpr int CH    = 512;   // C
static constexpr int CIc   = 256;   // inter channels
static constexpr int NSP   = 1024;  // H*W
#define EPSV 1e-5f

__device__ __forceinline__ bf16 f2bf(float f) { return __float2bfloat16(f); }

// async global->LDS, 16B per lane; LDS dest = wave-uniform base + lane*16
__device__ __forceinline__ void gload_lds16(const bf16* g, bf16* l) {
  __builtin_amdgcn_global_load_lds(
      (const __attribute__((address_space(1))) void*)g,
      (__attribute__((address_space(3))) void*)l, 16, 0, 0);
}

// ---------------- weight conversion ----------------
__global__ __launch_bounds__(256) void convert_weights(
    const float* __restrict__ wg, const float* __restrict__ wph, const float* __restrict__ wth,
    const float* __restrict__ bg, const float* __restrict__ bph, const float* __restrict__ bth,
    const float* __restrict__ wW,
    bf16* __restrict__ wcat, bf16* __restrict__ wWb, float* __restrict__ biascat)
{
  int i = blockIdx.x * 256 + threadIdx.x;
  const int WSZ = CIc * CH; // 131072
  if (i < WSZ) {
    wcat[i]         = f2bf(wg[i]);
    wcat[WSZ + i]   = f2bf(wph[i]);
    wcat[2*WSZ + i] = f2bf(wth[i]);
    wWb[i]          = f2bf(wW[i]);
  }
  if (i < CIc) {
    biascat[i]        = bg[i];
    biascat[CIc + i]  = bph[i];
    biascat[2*CIc + i]= bth[i];
  }
}

// ========== K1 FUSED: 256x128 NT GEMM, B staged straight from x (fp32, transposed) ====
// Identical compute structure to r8's gemm_bt<1>; the separate transpose_x kernel and
// the xt buffer are eliminated. Per K-tile each thread: col=tid>>2 (0..127),
// oct=tid&3; loads 8 scalar fp32 x[b][kb+oct*8+i][n0+col] (4KB stride; lines consumed
// within the tile -> L1/L2 absorb), packs bf16x8, one ds_write_b128 to
// Bs[col][ (oct ^ ((col>>1)&3)) *8 ] -- same involution the MFMA read path uses (rs).
// Write pattern: 2 cols per 128B -> conflict-free. T14: loads issue at loop top,
// ds_write after the MFMAs (latency hidden under compute).
// A = wcat staged via gload_lds16 exactly as r8. EPI1 epilogue unchanged.
__global__ __launch_bounds__(512, 4) void gemm_k1_fused(
    const bf16* __restrict__ A,          // wcat [768][512]
    const float* __restrict__ x,         // [32][512][1024] fp32
    bf16* __restrict__ Cm,               // proj [32][512][1024]
    const float* __restrict__ bias,      // bcat [768]
    bf16* __restrict__ Tt)               // thT [32][1024][256]
{
  constexpr int K = CH; // 512
  __shared__ bf16 As[2][256 * 32];   // 16KB per buf
  __shared__ bf16 Bs[2][128 * 32];   // 8KB per buf
  int bidx = blockIdx.x;                       // 768 = 8 XCD chunks x 96
  int wg = (bidx & 7) * 96 + (bidx >> 3);      // bijective (768 % 8 == 0)
  const int m0 = (wg >> 8) * 256;              // {0,256,512}
  const int ncol = (wg & 255);                 // global n-tile
  const int zb = ncol >> 3;                    // batch
  const int n0 = (ncol & 7) * 128;             // n within batch
  const float* xb = x + (size_t)zb * (CH * NSP);
  const int tid  = threadIdx.x;
  const int wv   = tid >> 6, lane = tid & 63;
  const int l16  = lane & 15, g4 = lane >> 4;
  const int wr   = wv >> 1,  wc = wv & 1;

  f32x4 acc[4][4];
  #pragma unroll
  for (int i = 0; i < 4; ++i)
    #pragma unroll
    for (int j = 0; j < 4; ++j)
      acc[i][j] = (f32x4){0.f, 0.f, 0.f, 0.f};

  // A staging (r8-identical): rows f*16+rq, source k-octet oct -> LDS slot lane.
  const int rq  = lane >> 2;
  const int aoct = (lane & 3) ^ ((lane >> 3) & 3);
  auto stageA = [&](int t, int p) {
    int kb = t * 32 + aoct * 8;
    #pragma unroll
    for (int i = 0; i < 2; ++i) {
      int f = wv * 2 + i;
      gload_lds16(A + (size_t)(m0 + f * 16 + rq) * K + kb, &As[p][f * 512]);
    }
  };

  // B staging from x (transposed): per thread one col, one octet.
  const int colq = tid >> 2;          // 0..127
  const int octq = tid & 3;           // 0..3
  const int bslot = octq ^ ((colq >> 1) & 3);
  float vb[8];
  auto loadB = [&](int t) {
    const float* xp = xb + (size_t)(t * 32 + octq * 8) * NSP + n0 + colq;
    #pragma unroll
    for (int i = 0; i < 8; ++i) vb[i] = xp[(size_t)i * NSP];
  };
  auto writeB = [&](int p) {
    short8v pk;
    #pragma unroll
    for (int i = 0; i < 8; ++i) {
      bf16 bv = f2bf(vb[i]);
      pk[i] = *(short*)&bv;
    }
    *(short8v*)&Bs[p][colq * 32 + bslot * 8] = pk;
  };

  const int rs = (g4 ^ ((l16 >> 1) & 3)) * 8;   // swizzled read slot
  const int nt = K >> 5;  // 16
  loadB(0); stageA(0, 0); writeB(0);
  __syncthreads();
  for (int t = 0; t < nt; ++t) {
    const int cur = t & 1;
    if (t + 1 < nt) { stageA(t + 1, cur ^ 1); loadB(t + 1); }   // issue early
    short8v af[4], bfv[4];
    #pragma unroll
    for (int mf = 0; mf < 4; ++mf)
      af[mf] = *(const short8v*)&As[cur][(wr * 64 + mf * 16 + l16) * 32 + rs];
    #pragma unroll
    for (int nf = 0; nf < 4; ++nf)
      bfv[nf] = *(const short8v*)&Bs[cur][(wc * 64 + nf * 16 + l16) * 32 + rs];
    #pragma unroll
    for (int mf = 0; mf < 4; ++mf)
      #pragma unroll
      for (int nf = 0; nf < 4; ++nf)
        acc[mf][nf] = __builtin_amdgcn_mfma_f32_16x16x32_bf16(af[mf], bfv[nf], acc[mf][nf], 0, 0, 0);
    if (t + 1 < nt) writeB(cur ^ 1);   // write late (loads had MFMA window)
    __syncthreads();
  }

  const int colbase = n0 + (zb << 10) + wc * 64 + l16;  // global col
  const int rowb    = wr * 64 + g4 * 4;

  if (m0 < 512) {
    #pragma unroll
    for (int mf = 0; mf < 4; ++mf)
      #pragma unroll
      for (int j = 0; j < 4; ++j) {
        int row = m0 + rowb + mf * 16 + j;
        float badd = bias[row];
        #pragma unroll
        for (int nf = 0; nf < 4; ++nf) {
          int col = colbase + nf * 16;
          int b = col >> 10, n = col & 1023;
          Cm[(size_t)b * (CH * NSP) + (size_t)row * NSP + n] = f2bf(acc[mf][nf][j] + badd);
        }
      }
  } else {
    // theta tile: transposed store thT[b][n][ci], 8B packed
    #pragma unroll
    for (int mf = 0; mf < 4; ++mf) {
      int ci0 = rowb + mf * 16;   // 0..255
      #pragma unroll
      for (int nf = 0; nf < 4; ++nf) {
        int col = colbase + nf * 16;
        int b = col >> 10, n = col & 1023;
        uint64_t pk = 0;
        #pragma unroll
        for (int j = 0; j < 4; ++j) {
          bf16 bv = f2bf(acc[mf][nf][j] + bias[512 + ci0 + j]);
          pk |= (uint64_t)(*(unsigned short*)&bv) << (16 * j);
        }
        *(uint64_t*)(Tt + (size_t)b * (NSP * CIc) + (size_t)n * CIc + ci0) = pk;
      }
    }
  }
}

// ========== 256x128 NT GEMM (r8), EPI2 epilogue — used for K4 ==========
__global__ __launch_bounds__(512, 4) void gemm_bt2(
    const bf16* __restrict__ A, size_t sA,
    const bf16* __restrict__ Bm, size_t sB,
    float* __restrict__ Cm,
    int K,
    const float* __restrict__ bW, const float* __restrict__ gma,
    const float* __restrict__ bta, const float* __restrict__ mu,
    const float* __restrict__ var,
    const float* __restrict__ xres)
{
  __shared__ bf16 As[2][256 * 32];
  __shared__ bf16 Bs[2][128 * 32];
  const int m0 = blockIdx.y * 256, n0 = blockIdx.x * 128, zb = blockIdx.z;
  const bf16* Ab = A  + (size_t)zb * sA;
  const bf16* Bb = Bm + (size_t)zb * sB;
  const int tid  = threadIdx.x;
  const int wv   = tid >> 6, lane = tid & 63;
  const int l16  = lane & 15, g4 = lane >> 4;
  const int wr   = wv >> 1,  wc = wv & 1;

  f32x4 acc[4][4];
  #pragma unroll
  for (int i = 0; i < 4; ++i)
    #pragma unroll
    for (int j = 0; j < 4; ++j)
      acc[i][j] = (f32x4){0.f, 0.f, 0.f, 0.f};

  const int rq  = lane >> 2;
  const int oct = (lane & 3) ^ ((lane >> 3) & 3);
  auto stage = [&](int t, int p) {
    int kb = t * 32 + oct * 8;
    #pragma unroll
    for (int i = 0; i < 2; ++i) {
      int f = wv * 2 + i;
      gload_lds16(Ab + (size_t)(m0 + f * 16 + rq) * K + kb, &As[p][f * 512]);
    }
    gload_lds16(Bb + (size_t)(n0 + wv * 16 + rq) * K + kb, &Bs[p][wv * 512]);
  };

  const int rs = (g4 ^ ((l16 >> 1) & 3)) * 8;
  const int nt = K >> 5;
  stage(0, 0);
  __syncthreads();
  for (int t = 0; t < nt; ++t) {
    const int cur = t & 1;
    if (t + 1 < nt) stage(t + 1, cur ^ 1);
    short8v af[4], bfv[4];
    #pragma unroll
    for (int mf = 0; mf < 4; ++mf)
      af[mf] = *(const short8v*)&As[cur][(wr * 64 + mf * 16 + l16) * 32 + rs];
    #pragma unroll
    for (int nf = 0; nf < 4; ++nf)
      bfv[nf] = *(const short8v*)&Bs[cur][(wc * 64 + nf * 16 + l16) * 32 + rs];
    #pragma unroll
    for (int mf = 0; mf < 4; ++mf)
      #pragma unroll
      for (int nf = 0; nf < 4; ++nf)
        acc[mf][nf] = __builtin_amdgcn_mfma_f32_16x16x32_bf16(af[mf], bfv[nf], acc[mf][nf], 0, 0, 0);
    __syncthreads();
  }

  const int colbase = n0 + wc * 64 + l16;
  const int rowb    = wr * 64 + g4 * 4;
  #pragma unroll
  for (int mf = 0; mf < 4; ++mf) {
    #pragma unroll
    for (int j = 0; j < 4; ++j) {
      int row = m0 + rowb + mf * 16 + j;
      float a  = gma[row] * rsqrtf(var[row] + EPSV);
      float bb = (bW[row] - mu[row]) * a + bta[row];
      float sc = a * (1.f / (float)NSP);
      #pragma unroll
      for (int nf = 0; nf < 4; ++nf) {
        int col = colbase + nf * 16;
        size_t idx = (size_t)zb * (CH * NSP) + (size_t)row * NSP + col;
        Cm[idx] = acc[mf][nf][j] * sc + bb + xres[idx];
      }
    }
  }
}

// ---------------- r3 2-phase 128x128 kernel (small GEMMs K2/K3) ----------------
__global__ __launch_bounds__(256) void gemm_nt_small(
    const bf16* __restrict__ A, size_t sA,
    const bf16* __restrict__ Bm, size_t sB,
    bf16* __restrict__ Cm, size_t sC,
    int N, int K)
{
  __shared__ bf16 As[2][128 * 64];
  __shared__ bf16 Bs[2][128 * 64];
  const int b  = blockIdx.z;
  const int m0 = blockIdx.y * 128;
  const int n0 = blockIdx.x * 128;
  const bf16* Ab = A  + (size_t)b * sA;
  const bf16* Bb = Bm + (size_t)b * sB;
  const int tid  = threadIdx.x;
  const int wv   = tid >> 6, lane = tid & 63;
  const int l16  = lane & 15, g4 = lane >> 4;
  const int wr   = wv >> 1,  wc = wv & 1;

  f32x4 acc[4][4];
  #pragma unroll
  for (int i = 0; i < 4; ++i)
    #pragma unroll
    for (int j = 0; j < 4; ++j)
      acc[i][j] = (f32x4){0.f, 0.f, 0.f, 0.f};

  auto stage = [&](int ks, int p) {
    #pragma unroll
    for (int i = 0; i < 4; ++i) {
      int s = i * 256 + tid;
      int row = s >> 3, ch8 = (s & 7) << 3;
      gload_lds16(Ab + (size_t)(m0 + row) * K + ks + ch8, &As[p][(i * 256 + wv * 64) * 8]);
      gload_lds16(Bb + (size_t)(n0 + row) * K + ks + ch8, &Bs[p][(i * 256 + wv * 64) * 8]);
    }
  };

  const int nt = K >> 6;
  stage(0, 0);
  __syncthreads();
  for (int t = 0; t < nt; ++t) {
    const int cur = t & 1;
    if (t + 1 < nt) stage((t + 1) << 6, cur ^ 1);
    #pragma unroll
    for (int kk = 0; kk < 2; ++kk) {
      short8v af[4], bfv[4];
      #pragma unroll
      for (int mf = 0; mf < 4; ++mf)
        af[mf] = *(const short8v*)&As[cur][(wr * 64 + mf * 16 + l16) * 64 + kk * 32 + g4 * 8];
      #pragma unroll
      for (int nf = 0; nf < 4; ++nf)
        bfv[nf] = *(const short8v*)&Bs[cur][(wc * 64 + nf * 16 + l16) * 64 + kk * 32 + g4 * 8];
      #pragma unroll
      for (int mf = 0; mf < 4; ++mf)
        #pragma unroll
        for (int nf = 0; nf < 4; ++nf)
          acc[mf][nf] = __builtin_amdgcn_mfma_f32_16x16x32_bf16(af[mf], bfv[nf], acc[mf][nf], 0, 0, 0);
    }
    __syncthreads();
  }

  const int colbase = n0 + wc * 64 + l16;
  const int rowbase = m0 + wr * 64 + g4 * 4;
  #pragma unroll
  for (int mf = 0; mf < 4; ++mf)
    #pragma unroll
    for (int j = 0; j < 4; ++j) {
      int row = rowbase + mf * 16 + j;
      #pragma unroll
      for (int nf = 0; nf < 4; ++nf) {
        int col = colbase + nf * 16;
        Cm[(size_t)b * sC + (size_t)row * N + col] = f2bf(acc[mf][nf][j]);
      }
    }
}

extern "C" void kernel_launch(void* const* d_in, const int* in_sizes, int n_in,
                              void* d_out, int out_size, void* d_ws, size_t ws_size,
                              hipStream_t stream)
{
  const float* x    = (const float*)d_in[0];
  const float* w_g  = (const float*)d_in[1];
  const float* b_g  = (const float*)d_in[2];
  const float* w_th = (const float*)d_in[3];
  const float* b_th = (const float*)d_in[4];
  const float* w_ph = (const float*)d_in[5];
  const float* b_ph = (const float*)d_in[6];
  const float* w_W  = (const float*)d_in[7];
  const float* b_W  = (const float*)d_in[8];
  const float* gma  = (const float*)d_in[9];
  const float* bta  = (const float*)d_in[10];
  const float* mu   = (const float*)d_in[11];
  const float* var  = (const float*)d_in[12];
  float* out = (float*)d_out;

  char* ws = (char*)d_ws;
  bf16* proj = (bf16*)(ws + 0);            // [32][512][1024]  g(0-255), phi(256-511)
  bf16* thT  = (bf16*)(ws + 67108864);     // [32][1024][256]
  bf16* S    = (bf16*)(ws + 83886080);     // [32][256][256]
  bf16* T    = (bf16*)(ws + 88080384);     // [32][512][256]
  bf16* wcat = (bf16*)(ws + 96468992);     // [768][512]
  bf16* wWb  = (bf16*)(ws + 97255424);     // [512][256]
  float* bcat= (float*)(ws + 97517568);    // [768]

  convert_weights<<<512, 256, 0, stream>>>(w_g, w_ph, w_th, b_g, b_ph, b_th, w_W, wcat, wWb, bcat);

  // K1 fused: [768 x 32768] = wcat . x^T (in-kernel transpose of x), 768 blocks
  gemm_k1_fused<<<dim3(768, 1, 1), 512, 0, stream>>>(wcat, x, proj, bcat, thT);

  // K2: S = phi . g^T   (M=256, N=256, K=1024) per batch
  gemm_nt_small<<<dim3(2, 2, 32), 256, 0, stream>>>(
      proj + 256 * 1024, (size_t)CH * NSP, proj, (size_t)CH * NSP, S, (size_t)CIc * CIc,
      CIc, NSP);

  // K3: T = wW . S^T    (M=512, N=256, K=256) per batch
  gemm_nt_small<<<dim3(2, 4, 32), 256, 0, stream>>>(
      wWb, 0, S, (size_t)CIc * CIc, T, (size_t)CH * CIc,
      CIc, CIc);

  // K4: out = BN(T . thT^T / N + bW) + x   (M=512, N=1024, K=256), 512 blocks
  gemm_bt2<<<dim3(8, 2, 32), 512, 0, stream>>>(
      T, (size_t)CH * CIc, thT, (size_t)NSP * CIc, out, CIc,
      b_W, gma, bta, mu, var, x);
}